// Round 1
// baseline (325.942 us; speedup 1.0000x reference)
//
#include <hip/hip_runtime.h>

#define STR 68  // LDS row stride (floats): 64 + 4 pad -> 16B-aligned, ~2-way banks

__global__ __launch_bounds__(256, 4) void fine_matching_kernel(
    const float* __restrict__ feat0, const float* __restrict__ feat1,
    float* __restrict__ out, int M)
{
  const int m    = blockIdx.x;
  const int t    = threadIdx.x;
  const int lane = t & 63;
  const int wave = t >> 6;

  __shared__ __align__(16) float s0buf[64 * STR];  // cls_f0 [pos][c]; later reused as sim[64][64]
  __shared__ __align__(16) float s1buf[64 * STR];  // cls_f1 inner [pos][c]
  __shared__ float rmax[64], rinv[64], cmax[64], cinv[64];
  __shared__ float redv[4];
  __shared__ int   redi[4];
  __shared__ int   sIdx;

  const float* f0m = feat0 + (size_t)m * 8192;    // 64*128
  const float* f1m = feat1 + (size_t)m * 12800;   // 100*128

  // ---------- Phase A: stage cls halves (first 64 channels) into LDS ----------
#pragma unroll
  for (int i = 0; i < 4; ++i) {
    int f  = i * 256 + t;          // float4 chunk id, 0..1023
    int p  = f >> 4;               // position 0..63
    int c4 = (f & 15) << 2;        // channel 0..60 step 4
    *(float4*)(&s0buf[p * STR + c4]) = *(const float4*)(f0m + p * 128 + c4);
    int row = (p >> 3) + 1, col = (p & 7) + 1;   // inner mask of 10x10
    *(float4*)(&s1buf[p * STR + c4]) = *(const float4*)(f1m + (row * 10 + col) * 128 + c4);
  }
  __syncthreads();

  // ---------- Phase B: sim[l][s] = dot64(f0[l], f1[s]) / 64 ; 4x4 tile/thread ----------
  const int s4 = (t & 15) << 2;    // s-tile base
  const int l4 = (t >> 4) << 2;    // l-tile base
  float acc[4][4] = {};
#pragma unroll 4
  for (int c = 0; c < 64; c += 4) {
    float4 a[4], b[4];
#pragma unroll
    for (int i = 0; i < 4; ++i) a[i] = *(float4*)(&s0buf[(l4 + i) * STR + c]);
#pragma unroll
    for (int j = 0; j < 4; ++j) b[j] = *(float4*)(&s1buf[(s4 + j) * STR + c]);
#pragma unroll
    for (int i = 0; i < 4; ++i)
#pragma unroll
      for (int j = 0; j < 4; ++j)
        acc[i][j] += a[i].x * b[j].x + a[i].y * b[j].y + a[i].z * b[j].z + a[i].w * b[j].w;
  }
  __syncthreads();  // done reading s0buf as f0 -> safe to overwrite with sim

  float* sim = s0buf;  // sim stored [l][64] (unpadded; rotated access below)
  const float sc = 1.0f / 64.0f;
#pragma unroll
  for (int i = 0; i < 4; ++i) {
    float4 v = make_float4(acc[i][0] * sc, acc[i][1] * sc, acc[i][2] * sc, acc[i][3] * sc);
    *(float4*)(&sim[(l4 + i) * 64 + s4]) = v;
  }
  __syncthreads();

  // ---------- Phase B2: row (axis s) and col (axis l) softmax stats ----------
  if (t < 64) {                         // wave 0: rows, lane = l
    int l = t;
    float mx = -1e30f;
#pragma unroll 8
    for (int k = 0; k < 64; ++k) mx = fmaxf(mx, sim[l * 64 + ((l + k) & 63)]);
    float sm = 0.0f;
#pragma unroll 8
    for (int k = 0; k < 64; ++k) sm += __expf(sim[l * 64 + ((l + k) & 63)] - mx);
    rmax[l] = mx; rinv[l] = 1.0f / sm;
  } else if (t < 128) {                 // wave 1: cols, lane = s
    int s = t - 64;
    float mx = -1e30f;
#pragma unroll 8
    for (int k = 0; k < 64; ++k) mx = fmaxf(mx, sim[((s + k) & 63) * 64 + s]);
    float sm = 0.0f;
#pragma unroll 8
    for (int k = 0; k < 64; ++k) sm += __expf(sim[((s + k) & 63) * 64 + s] - mx);
    cmax[s] = mx; cinv[s] = 1.0f / sm;
  }
  __syncthreads();

  // ---------- Phase B3: heatmap = exp(2*sim - rmax - cmax)*rinv*cinv; write + argmax ----------
  float best = -1.0f; int bidx = 0;
  float* outh = out + (size_t)m * 4096;
#pragma unroll
  for (int i = 0; i < 4; ++i) {
    int f  = i * 256 + t;
    int l  = f >> 4;
    int s0 = (f & 15) << 2;
    float4 v = *(float4*)(&sim[l * 64 + s0]);
    float rm = rmax[l], ri = rinv[l];
    float4 h;
    h.x = __expf(2.0f * v.x - rm - cmax[s0 + 0]) * ri * cinv[s0 + 0];
    h.y = __expf(2.0f * v.y - rm - cmax[s0 + 1]) * ri * cinv[s0 + 1];
    h.z = __expf(2.0f * v.z - rm - cmax[s0 + 2]) * ri * cinv[s0 + 2];
    h.w = __expf(2.0f * v.w - rm - cmax[s0 + 3]) * ri * cinv[s0 + 3];
    *(float4*)(outh + ((size_t)f << 2)) = h;
    int base = (l << 6) + s0;
    if (h.x > best) { best = h.x; bidx = base; }
    if (h.y > best) { best = h.y; bidx = base + 1; }
    if (h.z > best) { best = h.z; bidx = base + 2; }
    if (h.w > best) { best = h.w; bidx = base + 3; }
  }
  // wave-level argmax reduce (first-occurrence tie-break: lower index wins on ties)
#pragma unroll
  for (int off = 32; off; off >>= 1) {
    float ov = __shfl_xor(best, off);
    int   oi = __shfl_xor(bidx, off);
    if (ov > best || (ov == best && oi < bidx)) { best = ov; bidx = oi; }
  }
  if (lane == 0) { redv[wave] = best; redi[wave] = bidx; }
  __syncthreads();
  if (t == 0) {
#pragma unroll
    for (int w = 1; w < 4; ++w) {
      float ov = redv[w]; int oi = redi[w];
      if (ov > best || (ov == best && oi < bidx)) { best = ov; bidx = oi; }
    }
    sIdx = bidx;
    int i0 = bidx >> 6, i1 = bidx & 63;
    float* o = out + (size_t)M * 4096;
    o[m]         = (float)i0;                         // idxes0
    o[M + m]     = (float)i1;                         // idxes1
    o[2 * M + 2 * m + 0] = (float)(i0 & 7) - 3.5f;    // biases0.x
    o[2 * M + 2 * m + 1] = (float)(i0 >> 3) - 3.5f;   // biases0.y
    o[4 * M + 2 * m + 0] = (float)(i1 & 7) - 3.5f;    // biases1.x
    o[4 * M + 2 * m + 1] = (float)(i1 >> 3) - 3.5f;   // biases1.y
  }
  __syncthreads();

  // ---------- Phase C: reg refinement (wave 0; lane = channel) ----------
  if (wave == 0) {
    int bi = sIdx;
    int i0 = bi >> 6, i1 = bi & 63;
    float rf0 = f0m[i0 * 128 + 64 + lane];
    int r0 = i1 >> 3, c0 = i1 & 7;
    float p[9];
#pragma unroll
    for (int a = 0; a < 3; ++a)
#pragma unroll
      for (int b = 0; b < 3; ++b)
        p[a * 3 + b] = f1m[((r0 + a) * 10 + (c0 + b)) * 128 + 64 + lane] * rf0;
#pragma unroll
    for (int r = 0; r < 9; ++r)
#pragma unroll
      for (int off = 32; off; off >>= 1)
        p[r] += __shfl_xor(p[r], off);
    if (lane == 0) {
      float mx = p[0];
#pragma unroll
      for (int r = 1; r < 9; ++r) mx = fmaxf(mx, p[r]);
      float e[9], ssum = 0.0f;
#pragma unroll
      for (int r = 0; r < 9; ++r) { e[r] = __expf((p[r] - mx) * 0.125f); ssum += e[r]; }
      float inv = 1.0f / ssum, bx = 0.0f, by = 0.0f;
#pragma unroll
      for (int r = 0; r < 9; ++r) {
        float w = e[r] * inv;
        bx += w * (float)((r % 3) - 1);
        by += w * (float)((r / 3) - 1);
      }
      float* o = out + (size_t)M * 4096;
      o[6 * M + 2 * m + 0] = bx;
      o[6 * M + 2 * m + 1] = by;
    }
  }
}

extern "C" void kernel_launch(void* const* d_in, const int* in_sizes, int n_in,
                              void* d_out, int out_size, void* d_ws, size_t ws_size,
                              hipStream_t stream) {
  const float* f0 = (const float*)d_in[0];
  const float* f1 = (const float*)d_in[1];
  float* out = (float*)d_out;
  int M = in_sizes[0] / 8192;  // 64*128 per row
  fine_matching_kernel<<<dim3(M), dim3(256), 0, stream>>>(f0, f1, out, M);
}

// Round 2
// 263.178 us; speedup vs baseline: 1.2385x; 1.2385x over previous
//
#include <hip/hip_runtime.h>

#define STR 68  // LDS row stride (floats): keeps 16B alignment; rows 4-apart land 2-way (free)

__global__ __launch_bounds__(256, 4) void fine_matching_kernel(
    const float* __restrict__ feat0, const float* __restrict__ feat1,
    float* __restrict__ out, int M)
{
  const int m    = blockIdx.x;
  const int t    = threadIdx.x;
  const int lane = t & 63;
  const int wave = t >> 6;

  __shared__ __align__(16) float sa[64 * STR];    // cls_f0 [p][c]  (linear)
  __shared__ __align__(16) float sb[64 * STR];    // cls_f1 inner [p][c4 ^ ((p>>2)&7)<<2]  (XOR-swizzled)
  __shared__ __align__(16) float colpm[4][64];    // per-wave col-max partials
  __shared__ __align__(16) float colps[4][64];    // per-wave col-sum partials
  __shared__ float redv[4];
  __shared__ int   redi[4];
  __shared__ int   sIdx;

  const float* f0m = feat0 + (size_t)m * 8192;    // 64*128
  const float* f1m = feat1 + (size_t)m * 12800;   // 100*128

  // ---------- Phase A: stage cls halves into LDS (sb swizzled) ----------
#pragma unroll
  for (int i = 0; i < 4; ++i) {
    int f  = i * 256 + t;          // float4 chunk id, 0..1023
    int p  = f >> 4;               // position 0..63
    int c4 = (f & 15) << 2;        // channel 0..60 step 4
    *(float4*)(&sa[p * STR + c4]) = *(const float4*)(f0m + p * 128 + c4);
    int row = (p >> 3) + 1, col = (p & 7) + 1;    // inner mask of 10x10
    int xp  = ((p >> 2) & 7) << 2; // bank swizzle: spread rows 4-apart across quads
    *(float4*)(&sb[p * STR + (c4 ^ xp)]) = *(const float4*)(f1m + (row * 10 + col) * 128 + c4);
  }
  __syncthreads();

  // ---------- Phase B: sim 4x4 register tile per thread ----------
  const int st = t & 15, lt = t >> 4;
  const int s4 = st << 2, l4 = lt << 2;
  const int xs = (st & 7) << 2;    // read-side swizzle (== write-side xp for rows s4..s4+3)

  float acc[4][4] = {};
#pragma unroll 4
  for (int c = 0; c < 64; c += 4) {
    float4 a[4], b[4];
#pragma unroll
    for (int i = 0; i < 4; ++i) a[i] = *(float4*)(&sa[(l4 + i) * STR + c]);
#pragma unroll
    for (int j = 0; j < 4; ++j) b[j] = *(float4*)(&sb[(s4 + j) * STR + (c ^ xs)]);
#pragma unroll
    for (int i = 0; i < 4; ++i)
#pragma unroll
      for (int j = 0; j < 4; ++j)
        acc[i][j] += a[i].x * b[j].x + a[i].y * b[j].y + a[i].z * b[j].z + a[i].w * b[j].w;
  }

  const float sc = 1.0f / 64.0f;
#pragma unroll
  for (int i = 0; i < 4; ++i)
#pragma unroll
    for (int j = 0; j < 4; ++j) acc[i][j] *= sc;

  // ---------- softmax stats, in-register ----------
  // Row stats (reduce over s): threads sharing l4 are 16 consecutive lanes.
  float rmax[4], rinv[4];
#pragma unroll
  for (int i = 0; i < 4; ++i) {
    float rm = fmaxf(fmaxf(acc[i][0], acc[i][1]), fmaxf(acc[i][2], acc[i][3]));
#pragma unroll
    for (int off = 1; off <= 8; off <<= 1) rm = fmaxf(rm, __shfl_xor(rm, off));
    rmax[i] = rm;
  }
  // Col partial max (reduce over l): lanes xor {16,32} cover rows 16w..16w+15.
  {
    float cpm[4];
#pragma unroll
    for (int j = 0; j < 4; ++j) {
      float cm = fmaxf(fmaxf(acc[0][j], acc[1][j]), fmaxf(acc[2][j], acc[3][j]));
      cm = fmaxf(cm, __shfl_xor(cm, 16));
      cm = fmaxf(cm, __shfl_xor(cm, 32));
      cpm[j] = cm;
    }
    if (lane < 16) *(float4*)(&colpm[wave][s4]) = make_float4(cpm[0], cpm[1], cpm[2], cpm[3]);
  }
  __syncthreads();
  float cmaxv[4], cinv[4];
  {
    float4 q0 = *(float4*)(&colpm[0][s4]);
    float4 q1 = *(float4*)(&colpm[1][s4]);
    float4 q2 = *(float4*)(&colpm[2][s4]);
    float4 q3 = *(float4*)(&colpm[3][s4]);
    cmaxv[0] = fmaxf(fmaxf(q0.x, q1.x), fmaxf(q2.x, q3.x));
    cmaxv[1] = fmaxf(fmaxf(q0.y, q1.y), fmaxf(q2.y, q3.y));
    cmaxv[2] = fmaxf(fmaxf(q0.z, q1.z), fmaxf(q2.z, q3.z));
    cmaxv[3] = fmaxf(fmaxf(q0.w, q1.w), fmaxf(q2.w, q3.w));
  }

  // erow = exp(v - rmax) -> row sums; ecol = exp(v - cmax) overwrites acc -> col sums
  float erow[4][4];
#pragma unroll
  for (int i = 0; i < 4; ++i) {
    float rs = 0.0f;
#pragma unroll
    for (int j = 0; j < 4; ++j) { erow[i][j] = __expf(acc[i][j] - rmax[i]); rs += erow[i][j]; }
#pragma unroll
    for (int off = 1; off <= 8; off <<= 1) rs += __shfl_xor(rs, off);
    rinv[i] = 1.0f / rs;
  }
  {
    float cps[4];
#pragma unroll
    for (int j = 0; j < 4; ++j) {
      float cs = 0.0f;
#pragma unroll
      for (int i = 0; i < 4; ++i) { acc[i][j] = __expf(acc[i][j] - cmaxv[j]); cs += acc[i][j]; }
      cs += __shfl_xor(cs, 16);
      cs += __shfl_xor(cs, 32);
      cps[j] = cs;
    }
    if (lane < 16) *(float4*)(&colps[wave][s4]) = make_float4(cps[0], cps[1], cps[2], cps[3]);
  }
  __syncthreads();
  {
    float4 q0 = *(float4*)(&colps[0][s4]);
    float4 q1 = *(float4*)(&colps[1][s4]);
    float4 q2 = *(float4*)(&colps[2][s4]);
    float4 q3 = *(float4*)(&colps[3][s4]);
    cinv[0] = 1.0f / (q0.x + q1.x + q2.x + q3.x);
    cinv[1] = 1.0f / (q0.y + q1.y + q2.y + q3.y);
    cinv[2] = 1.0f / (q0.z + q1.z + q2.z + q3.z);
    cinv[3] = 1.0f / (q0.w + q1.w + q2.w + q3.w);
  }

  // ---------- heatmap write + argmax ----------
  float best = -1.0f; int bidx = 0;
  float* outh = out + (size_t)m * 4096;
#pragma unroll
  for (int i = 0; i < 4; ++i) {
    float ri = rinv[i];
    float4 h;
    h.x = erow[i][0] * acc[i][0] * ri * cinv[0];
    h.y = erow[i][1] * acc[i][1] * ri * cinv[1];
    h.z = erow[i][2] * acc[i][2] * ri * cinv[2];
    h.w = erow[i][3] * acc[i][3] * ri * cinv[3];
    int base = (l4 + i) * 64 + s4;
    *(float4*)(outh + base) = h;
    if (h.x > best) { best = h.x; bidx = base; }
    if (h.y > best) { best = h.y; bidx = base + 1; }
    if (h.z > best) { best = h.z; bidx = base + 2; }
    if (h.w > best) { best = h.w; bidx = base + 3; }
  }
  // wave argmax (tie-break: lower linear index, matches first-occurrence)
#pragma unroll
  for (int off = 32; off; off >>= 1) {
    float ov = __shfl_xor(best, off);
    int   oi = __shfl_xor(bidx, off);
    if (ov > best || (ov == best && oi < bidx)) { best = ov; bidx = oi; }
  }
  if (lane == 0) { redv[wave] = best; redi[wave] = bidx; }
  __syncthreads();
  if (t == 0) {
#pragma unroll
    for (int w = 1; w < 4; ++w) {
      float ov = redv[w]; int oi = redi[w];
      if (ov > best || (ov == best && oi < bidx)) { best = ov; bidx = oi; }
    }
    sIdx = bidx;
    int i0 = bidx >> 6, i1 = bidx & 63;
    float* o = out + (size_t)M * 4096;
    o[m]         = (float)i0;                         // idxes0
    o[M + m]     = (float)i1;                         // idxes1
    o[2 * M + 2 * m + 0] = (float)(i0 & 7) - 3.5f;    // biases0.x
    o[2 * M + 2 * m + 1] = (float)(i0 >> 3) - 3.5f;   // biases0.y
    o[4 * M + 2 * m + 0] = (float)(i1 & 7) - 3.5f;    // biases1.x
    o[4 * M + 2 * m + 1] = (float)(i1 >> 3) - 3.5f;   // biases1.y
  }
  __syncthreads();

  // ---------- Phase C: reg refinement (wave 0; lane = channel) ----------
  if (wave == 0) {
    int bi = sIdx;
    int i0 = bi >> 6, i1 = bi & 63;
    float rf0 = f0m[i0 * 128 + 64 + lane];
    int r0 = i1 >> 3, c0 = i1 & 7;
    float p[9];
#pragma unroll
    for (int a = 0; a < 3; ++a)
#pragma unroll
      for (int b = 0; b < 3; ++b)
        p[a * 3 + b] = f1m[((r0 + a) * 10 + (c0 + b)) * 128 + 64 + lane] * rf0;
#pragma unroll
    for (int r = 0; r < 9; ++r)
#pragma unroll
      for (int off = 32; off; off >>= 1)
        p[r] += __shfl_xor(p[r], off);
    if (lane == 0) {
      float mx = p[0];
#pragma unroll
      for (int r = 1; r < 9; ++r) mx = fmaxf(mx, p[r]);
      float e[9], ssum = 0.0f;
#pragma unroll
      for (int r = 0; r < 9; ++r) { e[r] = __expf((p[r] - mx) * 0.125f); ssum += e[r]; }
      float inv = 1.0f / ssum, bx = 0.0f, by = 0.0f;
#pragma unroll
      for (int r = 0; r < 9; ++r) {
        float w = e[r] * inv;
        bx += w * (float)((r % 3) - 1);
        by += w * (float)((r / 3) - 1);
      }
      float* o = out + (size_t)M * 4096;
      o[6 * M + 2 * m + 0] = bx;
      o[6 * M + 2 * m + 1] = by;
    }
  }
}

extern "C" void kernel_launch(void* const* d_in, const int* in_sizes, int n_in,
                              void* d_out, int out_size, void* d_ws, size_t ws_size,
                              hipStream_t stream) {
  const float* f0 = (const float*)d_in[0];
  const float* f1 = (const float*)d_in[1];
  float* out = (float*)d_out;
  int M = in_sizes[0] / 8192;  // 64*128 per row
  fine_matching_kernel<<<dim3(M), dim3(256), 0, stream>>>(f0, f1, out, M);
}